// Round 2
// baseline (10958.085 us; speedup 1.0000x reference)
//
#include <hip/hip_runtime.h>

// Neurcomp / SIREN MLP inference, fp32 VALU, lane-pair split.
// Two adjacent lanes share one point: even lane owns features [0,64),
// odd lane [64,128). Per-thread arrays are 64 elements -> reliable
// register promotion (round-1 failure mode: H[128]+z2[64] spilled to
// scratch, 9.5 GB of HBM traffic). K-split partials combined with one
// __shfl_xor(t,1). No LDS. Weights via float4 VMEM loads (L2-resident).

constexpr float OMEGA = 30.0f;
constexpr int HID  = 128;
constexpr int HH   = 64;           // features per lane (half)
constexpr int NRES = 7;
constexpr int JC   = 8;            // s1 chunk per kc iteration
constexpr int NKC  = HID / JC;     // 16
constexpr int BT   = 256;          // threads per block -> 128 points/block
constexpr int PPB  = BT / 2;       // points per block

__device__ __forceinline__ float sin_om(float z) {
    // sin(OMEGA * z): revolutions -> fract -> hardware v_sin_f32
    float r = z * (OMEGA * 0.15915494309189535f);
    r = r - floorf(r);
    return __builtin_amdgcn_sinf(r);
}

__global__ __launch_bounds__(BT, 2) void siren_kernel(
    const float* __restrict__ x,
    const float* __restrict__ w0, const float* __restrict__ b0,
    const float* __restrict__ rw1, const float* __restrict__ rb1,
    const float* __restrict__ rw2, const float* __restrict__ rb2,
    const float* __restrict__ wf, const float* __restrict__ bf,
    float* __restrict__ out, int n)
{
    const int tid  = threadIdx.x;
    const int half = tid & 1;                      // which feature half
    const int pt   = blockIdx.x * PPB + (tid >> 1);
    const int idx  = (pt < n) ? pt : (n - 1);      // clamp; store guarded
    const int base_o = half * HH;

    const float x0 = x[3 * idx + 0];
    const float x1 = x[3 * idx + 1];
    const float x2 = x[3 * idx + 2];

    // ---- first SineLayer: H[o] = sin(30*(w0[o]·x + b0[o])), o in my half
    float H[HH];
#pragma unroll
    for (int o = 0; o < HH; ++o) {
        const float* __restrict__ w = w0 + 3 * (base_o + o);
        float z = fmaf(w[0], x0, fmaf(w[1], x1, fmaf(w[2], x2, b0[base_o + o])));
        H[o] = sin_om(z);
    }

    for (int i = 0; i < NRES; ++i) {
        const float wgt1 = (i > 0) ? 0.5f : 1.0f;          // ave_first
        const float wgt2 = (i == NRES - 1) ? 0.5f : 1.0f;  // ave_second
        // W1: rows k' (all), my half of columns k
        const float* __restrict__ W1 = rw1 + i * HID * HID + half * HH;
        // W2: my half of rows o, all columns k'
        const float* __restrict__ W2 = rw2 + i * HID * HID + base_o * HID;
        const float* __restrict__ B1 = rb1 + i * HID;
        const float* __restrict__ B2 = rb2 + i * HID;

        float z2[HH];
#pragma unroll
        for (int o = 0; o < HH; ++o) z2[o] = B2[base_o + o];

        for (int kc = 0; kc < NKC; ++kc) {
            // ---- matmul1: sc[j] = sin(30*(wgt1*<W1[row],H_full> + b1[row]))
            float sc[JC];
#pragma unroll
            for (int j = 0; j < JC; ++j) {
                const int row = kc * JC + j;
                const float4* __restrict__ wr =
                    reinterpret_cast<const float4*>(W1 + row * HID);
                float a0 = 0.f, a1 = 0.f, a2 = 0.f, a3 = 0.f;
#pragma unroll
                for (int q = 0; q < HH / 4; ++q) {
                    float4 w4 = wr[q];
                    a0 = fmaf(w4.x, H[4 * q + 0], a0);
                    a1 = fmaf(w4.y, H[4 * q + 1], a1);
                    a2 = fmaf(w4.z, H[4 * q + 2], a2);
                    a3 = fmaf(w4.w, H[4 * q + 3], a3);
                }
                float t = (a0 + a1) + (a2 + a3);
                t += __shfl_xor(t, 1);                 // combine K halves
                sc[j] = sin_om(fmaf(wgt1, t, B1[row]));
            }
            // ---- matmul2 rank-JC update on my o-half
#pragma unroll
            for (int o = 0; o < HH; ++o) {
                const float4* __restrict__ wr =
                    reinterpret_cast<const float4*>(W2 + o * HID + kc * JC);
                float4 wa = wr[0];
                float4 wb = wr[1];
                float t = z2[o];
                t = fmaf(wa.x, sc[0], t);
                t = fmaf(wa.y, sc[1], t);
                t = fmaf(wa.z, sc[2], t);
                t = fmaf(wa.w, sc[3], t);
                t = fmaf(wb.x, sc[4], t);
                t = fmaf(wb.y, sc[5], t);
                t = fmaf(wb.z, sc[6], t);
                t = fmaf(wb.w, sc[7], t);
                z2[o] = t;
            }
        }

        // ---- epilogue: H = wgt2 * (H + sin(30*z2))   (b2 pre-folded)
#pragma unroll
        for (int o = 0; o < HH; ++o)
            H[o] = wgt2 * (H[o] + sin_om(z2[o]));
    }

    // ---- final linear head (split-K, shuffle combine)
    float acc = 0.f;
    const float4* __restrict__ wfv =
        reinterpret_cast<const float4*>(wf + base_o);
#pragma unroll
    for (int q = 0; q < HH / 4; ++q) {
        float4 w4 = wfv[q];
        acc = fmaf(w4.x, H[4 * q + 0], acc);
        acc = fmaf(w4.y, H[4 * q + 1], acc);
        acc = fmaf(w4.z, H[4 * q + 2], acc);
        acc = fmaf(w4.w, H[4 * q + 3], acc);
    }
    acc += __shfl_xor(acc, 1);
    if (pt < n && half == 0) out[pt] = acc + bf[0];
}

extern "C" void kernel_launch(void* const* d_in, const int* in_sizes, int n_in,
                              void* d_out, int out_size, void* d_ws, size_t ws_size,
                              hipStream_t stream) {
    const float* x   = (const float*)d_in[0];
    const float* w0  = (const float*)d_in[1];
    const float* b0  = (const float*)d_in[2];
    const float* rw1 = (const float*)d_in[3];
    const float* rb1 = (const float*)d_in[4];
    const float* rw2 = (const float*)d_in[5];
    const float* rb2 = (const float*)d_in[6];
    const float* wf  = (const float*)d_in[7];
    const float* bf  = (const float*)d_in[8];
    float* out = (float*)d_out;

    const int n = in_sizes[0] / 3;   // 200000
    const int grid = (n + PPB - 1) / PPB;
    siren_kernel<<<grid, BT, 0, stream>>>(x, w0, b0, rw1, rb1, rw2, rb2,
                                          wf, bf, out, n);
}

// Round 3
// 4940.063 us; speedup vs baseline: 2.2182x; 2.2182x over previous
//
#include <hip/hip_runtime.h>

// Neurcomp / SIREN MLP inference, fp32 VALU.
// One point per thread; wave-uniform weight indices -> scalar s_load path.
// KEY FIX vs rounds 1-2: template-recursion unrolling gives every private
// array access a compile-time-constant index at IR-gen time, so SROA
// promotes H[128]/z2r[64]/sc[8] to VGPRs (pragma-unroll loops left
// loop-variant indices at SROA time -> scratch spill -> VALUBusy 15%).
// z2 accumulator split 64 VGPR / 64 LDS (per-thread b64 slots, measured
// 0 bank conflicts in round 1). No shuffles, no per-lane weight loads.

constexpr float OMEGA = 30.0f;
constexpr int HID  = 128;
constexpr int NRES = 7;
constexpr int JC   = 8;            // s1 chunk per kc iteration
constexpr int NKC  = HID / JC;     // 16
constexpr int BT   = 256;          // threads per block
constexpr int ZREG = 64;           // z2 entries in registers
constexpr int ZLDS = HID - ZREG;   // z2 entries in LDS (64)

template <int I> struct IC { static constexpr int v = I; };

// Compile-time-unrolled loop: f receives IC<I>, so I is constexpr inside.
template <int N, int I = 0, typename F>
__device__ __forceinline__ void U(F&& f) {
    if constexpr (I < N) {
        f(IC<I>{});
        U<N, I + 1>(f);
    }
}

__device__ __forceinline__ float sin_om(float z) {
    // sin(OMEGA * z): revolutions -> fract -> hardware v_sin_f32
    float r = z * (OMEGA * 0.15915494309189535f);
    r = r - floorf(r);
    return __builtin_amdgcn_sinf(r);
}

__global__ __launch_bounds__(BT, 2) void siren_kernel(
    const float* __restrict__ x,
    const float* __restrict__ w0, const float* __restrict__ b0,
    const float* __restrict__ rw1, const float* __restrict__ rb1,
    const float* __restrict__ rw2, const float* __restrict__ rb2,
    const float* __restrict__ wf, const float* __restrict__ bf,
    float* __restrict__ out, int n)
{
    // [o-pair][2*tid + (0|1)]: 8B per thread per row -> conflict-free b64
    __shared__ float z2s[ZLDS / 2][2 * BT];

    const int tid = threadIdx.x;
    const int gid = blockIdx.x * BT + tid;
    const int idx = (gid < n) ? gid : (n - 1);   // clamp; store is guarded

    const float x0 = x[3 * idx + 0];
    const float x1 = x[3 * idx + 1];
    const float x2 = x[3 * idx + 2];

    float H[HID];
    U<HID>([&](auto o) {
        constexpr int oo = decltype(o)::v;
        float z = fmaf(w0[3 * oo + 0], x0,
                  fmaf(w0[3 * oo + 1], x1,
                  fmaf(w0[3 * oo + 2], x2, b0[oo])));
        H[oo] = sin_om(z);
    });

    for (int i = 0; i < NRES; ++i) {
        const float wgt1 = (i > 0) ? 0.5f : 1.0f;           // ave_first
        const float wgt2 = (i == NRES - 1) ? 0.5f : 1.0f;   // ave_second
        const float* __restrict__ W1 = rw1 + i * HID * HID;
        const float* __restrict__ W2 = rw2 + i * HID * HID;
        const float* __restrict__ B1 = rb1 + i * HID;
        const float* __restrict__ B2 = rb2 + i * HID;

        float z2r[ZREG];
        U<ZREG>([&](auto o) { z2r[decltype(o)::v] = B2[decltype(o)::v]; });
        U<ZLDS / 2>([&](auto p) {
            constexpr int pp = decltype(p)::v;
            z2s[pp][2 * tid + 0] = B2[ZREG + 2 * pp + 0];
            z2s[pp][2 * tid + 1] = B2[ZREG + 2 * pp + 1];
        });

        for (int kc = 0; kc < NKC; ++kc) {
            // ---- matmul1: sc[j] = sin(30*(wgt1*<W1[row],H> + b1[row]))
            float sc[JC];
            U<JC>([&](auto j) {
                constexpr int jj = decltype(j)::v;
                const float* __restrict__ w1r = W1 + (kc * JC + jj) * HID;
                float a0 = 0.f, a1 = 0.f;
                U<HID / 2>([&](auto q) {
                    constexpr int qq = decltype(q)::v;
                    a0 = fmaf(w1r[2 * qq + 0], H[2 * qq + 0], a0);
                    a1 = fmaf(w1r[2 * qq + 1], H[2 * qq + 1], a1);
                });
                sc[jj] = sin_om(fmaf(wgt1, a0 + a1, B1[kc * JC + jj]));
            });
            // ---- matmul2 rank-JC update, register half
            U<ZREG>([&](auto o) {
                constexpr int oo = decltype(o)::v;
                const float* __restrict__ w2r = W2 + oo * HID + kc * JC;
                float t = z2r[oo];
                U<JC>([&](auto j) {
                    constexpr int jj = decltype(j)::v;
                    t = fmaf(w2r[jj], sc[jj], t);
                });
                z2r[oo] = t;
            });
            // ---- matmul2, LDS half (private b64 slots)
            U<ZLDS / 2>([&](auto p) {
                constexpr int pp = decltype(p)::v;
                const int o = ZREG + 2 * pp;
                float2 v = *reinterpret_cast<float2*>(&z2s[pp][2 * tid]);
                const float* __restrict__ wa = W2 + (o + 0) * HID + kc * JC;
                const float* __restrict__ wb = W2 + (o + 1) * HID + kc * JC;
                U<JC>([&](auto j) {
                    constexpr int jj = decltype(j)::v;
                    v.x = fmaf(wa[jj], sc[jj], v.x);
                    v.y = fmaf(wb[jj], sc[jj], v.y);
                });
                *reinterpret_cast<float2*>(&z2s[pp][2 * tid]) = v;
            });
        }

        // ---- epilogue: H = wgt2 * (H + sin(30*z2))   (b2 pre-folded)
        U<ZREG>([&](auto o) {
            constexpr int oo = decltype(o)::v;
            H[oo] = wgt2 * (H[oo] + sin_om(z2r[oo]));
        });
        U<ZLDS / 2>([&](auto p) {
            constexpr int pp = decltype(p)::v;
            float2 v = *reinterpret_cast<float2*>(&z2s[pp][2 * tid]);
            H[ZREG + 2 * pp + 0] = wgt2 * (H[ZREG + 2 * pp + 0] + sin_om(v.x));
            H[ZREG + 2 * pp + 1] = wgt2 * (H[ZREG + 2 * pp + 1] + sin_om(v.y));
        });
    }

    // ---- final linear head
    float acc = bf[0];
    U<HID / 2>([&](auto q) {
        constexpr int qq = decltype(q)::v;
        acc = fmaf(wf[2 * qq + 0], H[2 * qq + 0],
              fmaf(wf[2 * qq + 1], H[2 * qq + 1], acc));
    });
    if (gid < n) out[gid] = acc;
}

extern "C" void kernel_launch(void* const* d_in, const int* in_sizes, int n_in,
                              void* d_out, int out_size, void* d_ws, size_t ws_size,
                              hipStream_t stream) {
    const float* x   = (const float*)d_in[0];
    const float* w0  = (const float*)d_in[1];
    const float* b0  = (const float*)d_in[2];
    const float* rw1 = (const float*)d_in[3];
    const float* rb1 = (const float*)d_in[4];
    const float* rw2 = (const float*)d_in[5];
    const float* rb2 = (const float*)d_in[6];
    const float* wf  = (const float*)d_in[7];
    const float* bf  = (const float*)d_in[8];
    float* out = (float*)d_out;

    const int n = in_sizes[0] / 3;   // 200000
    const int grid = (n + BT - 1) / BT;
    siren_kernel<<<grid, BT, 0, stream>>>(x, w0, b0, rw1, rb1, rw2, rb2,
                                          wf, bf, out, n);
}

// Round 5
// 4066.956 us; speedup vs baseline: 2.6944x; 1.2147x over previous
//
#include <hip/hip_runtime.h>

// Neurcomp / SIREN MLP inference, fp32 VALU, round 5.
// History: r1-r3 kept per-thread state in C arrays -> allocas never
// promoted (VGPR_Count=112, scratch-bound, VALUBusy ~15%). r4's nested
// REP macros hit preprocessor blue-paint (recursive family). Fix here:
// ALL per-thread state is individually named scalars (H0..H127, Z0..Z63,
// S0..S7) generated by explicit literal X-macro lists with distinct
// families per nesting level. Pure SSA -> nothing to spill structurally.
// One point/thread; wave-uniform weight indices -> scalar s_load path;
// z2 split 64 regs / 64 LDS ([p][2*tid] b64 slots, 0 bank conflicts).

constexpr float OMEGA = 30.0f;
constexpr int HID  = 128;
constexpr int NRES = 7;
constexpr int JC   = 8;            // s1 chunk per kc iteration
constexpr int NKC  = HID / JC;     // 16
constexpr int BT   = 256;          // threads per block

// ---- literal repetition lists (no recursion, token-paste safe) ----
#define L8(M)  M(0) M(1) M(2) M(3) M(4) M(5) M(6) M(7)
#define L32(M) M(0) M(1) M(2) M(3) M(4) M(5) M(6) M(7) M(8) M(9) M(10) \
  M(11) M(12) M(13) M(14) M(15) M(16) M(17) M(18) M(19) M(20) M(21) \
  M(22) M(23) M(24) M(25) M(26) M(27) M(28) M(29) M(30) M(31)
#define L64(M) M(0) M(1) M(2) M(3) M(4) M(5) M(6) M(7) M(8) M(9) M(10) \
  M(11) M(12) M(13) M(14) M(15) M(16) M(17) M(18) M(19) M(20) M(21) \
  M(22) M(23) M(24) M(25) M(26) M(27) M(28) M(29) M(30) M(31) M(32) \
  M(33) M(34) M(35) M(36) M(37) M(38) M(39) M(40) M(41) M(42) M(43) \
  M(44) M(45) M(46) M(47) M(48) M(49) M(50) M(51) M(52) M(53) M(54) \
  M(55) M(56) M(57) M(58) M(59) M(60) M(61) M(62) M(63)
#define L64H(M) M(64) M(65) M(66) M(67) M(68) M(69) M(70) M(71) M(72) \
  M(73) M(74) M(75) M(76) M(77) M(78) M(79) M(80) M(81) M(82) M(83) \
  M(84) M(85) M(86) M(87) M(88) M(89) M(90) M(91) M(92) M(93) M(94) \
  M(95) M(96) M(97) M(98) M(99) M(100) M(101) M(102) M(103) M(104) \
  M(105) M(106) M(107) M(108) M(109) M(110) M(111) M(112) M(113) \
  M(114) M(115) M(116) M(117) M(118) M(119) M(120) M(121) M(122) \
  M(123) M(124) M(125) M(126) M(127)
#define L128(M) L64(M) L64H(M)
// pairs (p, 64+2p, 65+2p) for the LDS-half epilogue
#define LP32(M) M(0,64,65) M(1,66,67) M(2,68,69) M(3,70,71) M(4,72,73) \
  M(5,74,75) M(6,76,77) M(7,78,79) M(8,80,81) M(9,82,83) M(10,84,85) \
  M(11,86,87) M(12,88,89) M(13,90,91) M(14,92,93) M(15,94,95) \
  M(16,96,97) M(17,98,99) M(18,100,101) M(19,102,103) M(20,104,105) \
  M(21,106,107) M(22,108,109) M(23,110,111) M(24,112,113) M(25,114,115) \
  M(26,116,117) M(27,118,119) M(28,120,121) M(29,122,123) M(30,124,125) \
  M(31,126,127)

__device__ __forceinline__ float sin_om(float z) {
    // sin(OMEGA * z): revolutions -> fract -> hardware v_sin_f32
    float r = z * (OMEGA * 0.15915494309189535f);
    r = r - floorf(r);
    return __builtin_amdgcn_sinf(r);
}

__global__ __launch_bounds__(BT, 2) void siren_kernel(
    const float* __restrict__ x,
    const float* __restrict__ w0, const float* __restrict__ b0,
    const float* __restrict__ rw1, const float* __restrict__ rb1,
    const float* __restrict__ rw2, const float* __restrict__ rb2,
    const float* __restrict__ wf, const float* __restrict__ bf,
    float* __restrict__ out, int n)
{
    // z2 high half: [o-pair][2*tid + (0|1)] -> conflict-free b64 slots
    __shared__ float z2s[32][2 * BT];

    const int tid = threadIdx.x;
    const int gid = blockIdx.x * BT + tid;
    const int idx = (gid < n) ? gid : (n - 1);   // clamp; store is guarded

    const float x0 = x[3 * idx + 0];
    const float x1 = x[3 * idx + 1];
    const float x2 = x[3 * idx + 2];

    // ---- named scalar state: H0..H127, Z0..Z63 ----
#define DECLH(o) float H##o;
    L128(DECLH)
#define DECLZ(o) float Z##o;
    L64(DECLZ)

    // ---- first SineLayer: H[o] = sin(30*(w0[o]·x + b0[o])) ----
#define FL(o) { float z = fmaf(w0[3*(o)+0], x0, fmaf(w0[3*(o)+1], x1, \
                fmaf(w0[3*(o)+2], x2, b0[(o)]))); H##o = sin_om(z); }
    L128(FL)

    for (int i = 0; i < NRES; ++i) {
        const float wgt1 = (i > 0) ? 0.5f : 1.0f;           // ave_first
        const float wgt2 = (i == NRES - 1) ? 0.5f : 1.0f;   // ave_second
        const float* __restrict__ W1 = rw1 + i * HID * HID;
        const float* __restrict__ W2 = rw2 + i * HID * HID;
        const float* __restrict__ B1 = rb1 + i * HID;
        const float* __restrict__ B2 = rb2 + i * HID;

        // z2 init: low 64 in registers, high 64 in LDS
#define ZI(o) Z##o = B2[(o)];
        L64(ZI)
#define ZSI(p) { z2s[(p)][2*tid+0] = B2[64+2*(p)+0]; \
                 z2s[(p)][2*tid+1] = B2[64+2*(p)+1]; }
        L32(ZSI)

        for (int kc = 0; kc < NKC; ++kc) {
            const float* __restrict__ W1c = W1 + kc * JC * HID;
            const float* __restrict__ B1c = B1 + kc * JC;
            const float* __restrict__ W2c = W2 + kc * JC;

            // ---- matmul1: S_j = sin(30*(wgt1*<W1row, H> + b1row)) ----
#define DECLS(j) float S##j;
            L8(DECLS)
#define M1A(k) a0 = fmaf(wr[(k)], H##k, a0);
#define M1B(k) a1 = fmaf(wr[(k)], H##k, a1);
#define MM1(j) { const float* __restrict__ wr = W1c + (j) * HID; \
                 float a0 = 0.f, a1 = 0.f; \
                 L64(M1A) L64H(M1B) \
                 S##j = sin_om(fmaf(wgt1, a0 + a1, B1c[(j)])); }
            L8(MM1)

            // ---- matmul2 rank-8 update, register half (o in [0,64)) ----
#define M2J(j) t = fmaf(wr2[(j)], S##j, t);
#define MM2(o) { const float* __restrict__ wr2 = W2c + (o) * HID; \
                 float t = Z##o; L8(M2J) Z##o = t; }
            L64(MM2)

            // ---- matmul2, LDS half (o in [64,128), b64 private slots) ----
#define M2LJ(j) { v.x = fmaf(wra[(j)], S##j, v.x); \
                  v.y = fmaf(wrb[(j)], S##j, v.y); }
#define MM2L(p) { const float* __restrict__ wra = W2c + (64+2*(p)) * HID; \
                  const float* __restrict__ wrb = wra + HID; \
                  float2 v = *(float2*)(&z2s[(p)][2*tid]); \
                  L8(M2LJ) \
                  *(float2*)(&z2s[(p)][2*tid]) = v; }
            L32(MM2L)
        }

        // ---- epilogue: H = wgt2 * (H + sin(30*z2)) ----
#define EPLO(o) H##o = wgt2 * (H##o + sin_om(Z##o));
        L64(EPLO)
#define EPHI(p, a, b) { float2 v = *(float2*)(&z2s[(p)][2*tid]); \
                        H##a = wgt2 * (H##a + sin_om(v.x)); \
                        H##b = wgt2 * (H##b + sin_om(v.y)); }
        LP32(EPHI)
    }

    // ---- final linear head ----
    float acc = bf[0], acc2 = 0.f;
#define HDA(k) acc  = fmaf(wf[(k)], H##k, acc);
#define HDB(k) acc2 = fmaf(wf[(k)], H##k, acc2);
    L64(HDA)
    L64H(HDB)
    if (gid < n) out[gid] = acc + acc2;
}

extern "C" void kernel_launch(void* const* d_in, const int* in_sizes, int n_in,
                              void* d_out, int out_size, void* d_ws, size_t ws_size,
                              hipStream_t stream) {
    const float* x   = (const float*)d_in[0];
    const float* w0  = (const float*)d_in[1];
    const float* b0  = (const float*)d_in[2];
    const float* rw1 = (const float*)d_in[3];
    const float* rb1 = (const float*)d_in[4];
    const float* rw2 = (const float*)d_in[5];
    const float* rb2 = (const float*)d_in[6];
    const float* wf  = (const float*)d_in[7];
    const float* bf  = (const float*)d_in[8];
    float* out = (float*)d_out;

    const int n = in_sizes[0] / 3;   // 200000
    const int grid = (n + BT - 1) / BT;
    siren_kernel<<<grid, BT, 0, stream>>>(x, w0, b0, rw1, rb1, rw2, rb2,
                                          wf, bf, out, n);
}

// Round 6
// 397.831 us; speedup vs baseline: 27.5446x; 10.2228x over previous
//
#include <hip/hip_runtime.h>

// Neurcomp / SIREN MLP inference — round 6: MFMA (bf16 hi/lo split x3).
// r1-r5 post-mortem: one-point-per-thread fp32 VALU needs ~210 live
// VGPRs/lane; backend caps at 128 and spills (VALUBusy ~15%). Pivot to
// wave-cooperative MFMA: 1 wave = 32 points (2 M-tiles of 16), layer
// matmuls on the 2.5 PF matrix pipe via 16x16x32 bf16, split precision
// (hi+lo bf16, 3 MFMAs) for fp32-grade accuracy. Prep kernel pre-splits
// + pre-swizzles weights into B-fragment order in d_ws (rerun every
// launch; wgt1 folded in). Activations round-trip C-layout -> LDS
// (packed hi/lo u32, wave-private, no barriers) -> A-fragments.
// Layouts (verified, learn_hip m89/m120): A[m=lane&15][k=(lane>>4)*8+j],
// B[k=(lane>>4)*8+j][n=lane&15], C/D col=lane&15 row=(lane>>4)*4+reg.

typedef unsigned int u32;
typedef short s8v __attribute__((ext_vector_type(8)));   // 8 bf16 (bits)
typedef float f4v __attribute__((ext_vector_type(4)));
typedef u32   u4v __attribute__((ext_vector_type(4)));

constexpr float OMEGA = 30.0f;
constexpr int HID = 128, NRES = 7, BT = 256;
constexpr int STRIDE = 132;           // u32 per LDS row (16B-aligned, pad)
constexpr int WAVE_LDS = 32 * STRIDE; // 4224 u32 per wave
constexpr int FRAG_ELEMS = 14 * 16384;  // bf16 elems per hi/lo ws array

__device__ __forceinline__ float sin_om(float z) {
    float r = z * (OMEGA * 0.15915494309189535f);
    r = r - floorf(r);
    return __builtin_amdgcn_sinf(r);
}

__device__ __forceinline__ f4v mfma16(s8v a, s8v b, f4v c) {
    return __builtin_amdgcn_mfma_f32_16x16x32_bf16(a, b, c, 0, 0, 0);
}

// split fp32 -> (hi bf16 | lo bf16) packed in one u32 (hi in top 16)
__device__ __forceinline__ u32 packf(float f) {
    u32 b = __builtin_bit_cast(u32, f);
    u32 hb = b & 0xffff0000u;
    float lo = f - __builtin_bit_cast(float, hb);
    return hb | (__builtin_bit_cast(u32, lo) >> 16);
}

// 8 packed u32 (2x u4v) -> hi short8 + lo short8
#define FRAGS(A_, B_, FH_, FL_) { u4v h_, l_; \
    h_.x = (A_.x >> 16) | (A_.y & 0xffff0000u); l_.x = (A_.x & 0xffffu) | (A_.y << 16); \
    h_.y = (A_.z >> 16) | (A_.w & 0xffff0000u); l_.y = (A_.z & 0xffffu) | (A_.w << 16); \
    h_.z = (B_.x >> 16) | (B_.y & 0xffff0000u); l_.z = (B_.x & 0xffffu) | (B_.y << 16); \
    h_.w = (B_.z >> 16) | (B_.w & 0xffff0000u); l_.w = (B_.z & 0xffffu) | (B_.w << 16); \
    FH_ = __builtin_bit_cast(s8v, h_); FL_ = __builtin_bit_cast(s8v, l_); }

// ---- repetition lists ----
#define LMR8(M) M(0,0) M(0,1) M(0,2) M(0,3) M(1,0) M(1,1) M(1,2) M(1,3)
#define LNT8(M) M(0) M(1) M(2) M(3) M(4) M(5) M(6) M(7)
#define LAF8(M) M(0,0) M(0,1) M(0,2) M(0,3) M(1,0) M(1,1) M(1,2) M(1,3)
#define LH64(M) \
  M(0,0,0) M(0,0,1) M(0,0,2) M(0,0,3) M(0,1,0) M(0,1,1) M(0,1,2) M(0,1,3) \
  M(0,2,0) M(0,2,1) M(0,2,2) M(0,2,3) M(0,3,0) M(0,3,1) M(0,3,2) M(0,3,3) \
  M(0,4,0) M(0,4,1) M(0,4,2) M(0,4,3) M(0,5,0) M(0,5,1) M(0,5,2) M(0,5,3) \
  M(0,6,0) M(0,6,1) M(0,6,2) M(0,6,3) M(0,7,0) M(0,7,1) M(0,7,2) M(0,7,3) \
  M(1,0,0) M(1,0,1) M(1,0,2) M(1,0,3) M(1,1,0) M(1,1,1) M(1,1,2) M(1,1,3) \
  M(1,2,0) M(1,2,1) M(1,2,2) M(1,2,3) M(1,3,0) M(1,3,1) M(1,3,2) M(1,3,3) \
  M(1,4,0) M(1,4,1) M(1,4,2) M(1,4,3) M(1,5,0) M(1,5,1) M(1,5,2) M(1,5,3) \
  M(1,6,0) M(1,6,1) M(1,6,2) M(1,6,3) M(1,7,0) M(1,7,1) M(1,7,2) M(1,7,3)
#define LT8(M) \
  M(0, H_0_0_0,H_0_0_1,H_0_0_2,H_0_0_3, H_1_0_0,H_1_0_1,H_1_0_2,H_1_0_3) \
  M(1, H_0_1_0,H_0_1_1,H_0_1_2,H_0_1_3, H_1_1_0,H_1_1_1,H_1_1_2,H_1_1_3) \
  M(2, H_0_2_0,H_0_2_1,H_0_2_2,H_0_2_3, H_1_2_0,H_1_2_1,H_1_2_2,H_1_2_3) \
  M(3, H_0_3_0,H_0_3_1,H_0_3_2,H_0_3_3, H_1_3_0,H_1_3_1,H_1_3_2,H_1_3_3) \
  M(4, H_0_4_0,H_0_4_1,H_0_4_2,H_0_4_3, H_1_4_0,H_1_4_1,H_1_4_2,H_1_4_3) \
  M(5, H_0_5_0,H_0_5_1,H_0_5_2,H_0_5_3, H_1_5_0,H_1_5_1,H_1_5_2,H_1_5_3) \
  M(6, H_0_6_0,H_0_6_1,H_0_6_2,H_0_6_3, H_1_6_0,H_1_6_1,H_1_6_2,H_1_6_3) \
  M(7, H_0_7_0,H_0_7_1,H_0_7_2,H_0_7_3, H_1_7_0,H_1_7_1,H_1_7_2,H_1_7_3)

// ---- weight prep: fp32 W -> hi/lo bf16 B-fragments in d_ws ----
// frag elem offset for (L,t,kc,lane,j) = 8*(L*2048 + t*256 + kc*64 + lane) + j
__global__ void prep_kernel(const float* __restrict__ rw1,
                            const float* __restrict__ rw2,
                            unsigned short* __restrict__ wsHi,
                            unsigned short* __restrict__ wsLo) {
    int id = blockIdx.x * 256 + threadIdx.x;      // 0 .. 28671
    int lane = id & 63, kc = (id >> 6) & 3, t = (id >> 8) & 7, L = id >> 11;
    int i = L >> 1;
    bool isW1 = ((L & 1) == 0);
    const float* W = (isW1 ? rw1 : rw2) + i * HID * HID;
    float sc = (isW1 && i > 0) ? 0.5f : 1.0f;     // fold wgt1 (ave_first)
    int n = t * 16 + (lane & 15);                  // output feature
    int k0 = kc * 32 + (lane >> 4) * 8;            // input feature base
    const float* src = W + n * HID + k0;           // W[n][k0..k0+7]
    int off = id * 8;
    for (int j = 0; j < 8; ++j) {
        float w = src[j] * sc;
        u32 b = __builtin_bit_cast(u32, w);
        u32 hb = b & 0xffff0000u;
        float lo = w - __builtin_bit_cast(float, hb);
        wsHi[off + j] = (unsigned short)(b >> 16);
        wsLo[off + j] = (unsigned short)(__builtin_bit_cast(u32, lo) >> 16);
    }
}

__global__ void __launch_bounds__(BT)
__attribute__((amdgpu_waves_per_eu(2, 2)))
siren_mfma(const float* __restrict__ x,
           const float* __restrict__ w0p, const float* __restrict__ b0p,
           const float* __restrict__ b1p, const float* __restrict__ b2p,
           const float* __restrict__ wfp, const float* __restrict__ bfp,
           const u4v* __restrict__ whi, const u4v* __restrict__ wlo,
           float* __restrict__ out, int NP)
{
    __shared__ u32 buf[4 * WAVE_LDS];              // 67584 B, wave-private

    const int tid = threadIdx.x;
    const int wv = tid >> 6, lane = tid & 63;
    const int ln = lane & 15, q = lane >> 4;
    const int q4 = q * 4, q8 = q * 8;
    const int wb = wv * WAVE_LDS;
    const int base_pt = blockIdx.x * 128 + wv * 32;

    // ---- first SineLayer (fp32 VALU), H in C-layout named registers ----
#define LX(mt,reg) float X_##mt##_##reg, Y_##mt##_##reg, Z_##mt##_##reg; \
    { int pt_ = base_pt + mt*16 + q4 + reg; int ix_ = pt_ < NP ? pt_ : NP-1; \
      X_##mt##_##reg = x[3*ix_+0]; Y_##mt##_##reg = x[3*ix_+1]; \
      Z_##mt##_##reg = x[3*ix_+2]; }
    LMR8(LX)
#define LW(nt) float WA##nt = w0p[3*(nt*16+ln)+0], WB##nt = w0p[3*(nt*16+ln)+1], \
    WC##nt = w0p[3*(nt*16+ln)+2], BB##nt = b0p[nt*16+ln];
    LNT8(LW)
#define FL0(mt,nt,reg) float H_##mt##_##nt##_##reg = sin_om( \
    fmaf(WA##nt, X_##mt##_##reg, fmaf(WB##nt, Y_##mt##_##reg, \
    fmaf(WC##nt, Z_##mt##_##reg, BB##nt))));
    LH64(FL0)

    // A-fragment registers (hi/lo) for 2 M-tiles x 4 k-chunks
    s8v FH00, FH01, FH02, FH03, FH10, FH11, FH12, FH13;
    s8v FL00, FL01, FL02, FL03, FL10, FL11, FL12, FL13;

#define WH(mt,nt,reg) buf[wb + (mt*16 + q4 + reg)*STRIDE + nt*16 + ln] = \
    packf(H_##mt##_##nt##_##reg);
#define RF(mt,kc) { const u32* p_ = &buf[wb + (mt*16+ln)*STRIDE + kc*32 + q8]; \
    u4v a_ = *(const u4v*)p_; u4v b_ = *(const u4v*)(p_+4); \
    FRAGS(a_, b_, FH##mt##kc, FL##mt##kc) }

#define ST5(t, ea0,ea1,ea2,ea3, eb0,eb1,eb2,eb3) { \
    const int fb = (L2*32 + t*4)*64 + lane; \
    u4v g0 = whi[fb], g1 = whi[fb+64], g2 = whi[fb+128], g3 = whi[fb+192]; \
    u4v r0 = wlo[fb], r1 = wlo[fb+64], r2 = wlo[fb+128], r3 = wlo[fb+192]; \
    float bv = B2l[t*16 + ln]; \
    f4v c0 = {bv,bv,bv,bv}, c1 = c0; \
    s8v bh, bl; \
    bh = __builtin_bit_cast(s8v, g0); bl = __builtin_bit_cast(s8v, r0); \
    c0 = mfma16(FH00, bh, c0); c0 = mfma16(FL00, bh, c0); c0 = mfma16(FH00, bl, c0); \
    c1 = mfma16(FH10, bh, c1); c1 = mfma16(FL10, bh, c1); c1 = mfma16(FH10, bl, c1); \
    bh = __builtin_bit_cast(s8v, g1); bl = __builtin_bit_cast(s8v, r1); \
    c0 = mfma16(FH01, bh, c0); c0 = mfma16(FL01, bh, c0); c0 = mfma16(FH01, bl, c0); \
    c1 = mfma16(FH11, bh, c1); c1 = mfma16(FL11, bh, c1); c1 = mfma16(FH11, bl, c1); \
    bh = __builtin_bit_cast(s8v, g2); bl = __builtin_bit_cast(s8v, r2); \
    c0 = mfma16(FH02, bh, c0); c0 = mfma16(FL02, bh, c0); c0 = mfma16(FH02, bl, c0); \
    c1 = mfma16(FH12, bh, c1); c1 = mfma16(FL12, bh, c1); c1 = mfma16(FH12, bl, c1); \
    bh = __builtin_bit_cast(s8v, g3); bl = __builtin_bit_cast(s8v, r3); \
    c0 = mfma16(FH03, bh, c0); c0 = mfma16(FL03, bh, c0); c0 = mfma16(FH03, bl, c0); \
    c1 = mfma16(FH13, bh, c1); c1 = mfma16(FL13, bh, c1); c1 = mfma16(FH13, bl, c1); \
    ea0 = wgt2 * (ea0 + sin_om(c0.x)); \
    ea1 = wgt2 * (ea1 + sin_om(c0.y)); \
    ea2 = wgt2 * (ea2 + sin_om(c0.z)); \
    ea3 = wgt2 * (ea3 + sin_om(c0.w)); \
    eb0 = wgt2 * (eb0 + sin_om(c1.x)); \
    eb1 = wgt2 * (eb1 + sin_om(c1.y)); \
    eb2 = wgt2 * (eb2 + sin_om(c1.z)); \
    eb3 = wgt2 * (eb3 + sin_om(c1.w)); }

    for (int i = 0; i < NRES; ++i) {
        const int L1 = 2 * i, L2 = 2 * i + 1;
        const float* __restrict__ B1l = b1p + i * HID;
        const float* __restrict__ B2l = b2p + i * HID;
        const float wgt2 = (i == NRES - 1) ? 0.5f : 1.0f;   // ave_second

        LH64(WH)        // h (C-layout regs) -> LDS [m][k], packed hi/lo
        LAF8(RF)        // h A-fragments

        // ---- matmul1 -> s1 (sine applied), stored back to LDS ----
        for (int t = 0; t < 8; ++t) {
            const int fb = (L1*32 + t*4)*64 + lane;
            u4v g0 = whi[fb], g1 = whi[fb+64], g2 = whi[fb+128], g3 = whi[fb+192];
            u4v r0 = wlo[fb], r1 = wlo[fb+64], r2 = wlo[fb+128], r3 = wlo[fb+192];
            float bv = B1l[t*16 + ln];
            f4v c0 = {bv,bv,bv,bv}, c1 = c0;
            s8v bh, bl;
            bh = __builtin_bit_cast(s8v, g0); bl = __builtin_bit_cast(s8v, r0);
            c0 = mfma16(FH00, bh, c0); c0 = mfma16(FL00, bh, c0); c0 = mfma16(FH00, bl, c0);
            c1 = mfma16(FH10, bh, c1); c1 = mfma16(FL10, bh, c1); c1 = mfma16(FH10, bl, c1);
            bh = __builtin_bit_cast(s8v, g1); bl = __builtin_bit_cast(s8v, r1);
            c0 = mfma16(FH01, bh, c0); c0 = mfma16(FL01, bh, c0); c0 = mfma16(FH01, bl, c0);
            c1 = mfma16(FH11, bh, c1); c1 = mfma16(FL11, bh, c1); c1 = mfma16(FH11, bl, c1);
            bh = __builtin_bit_cast(s8v, g2); bl = __builtin_bit_cast(s8v, r2);
            c0 = mfma16(FH02, bh, c0); c0 = mfma16(FL02, bh, c0); c0 = mfma16(FH02, bl, c0);
            c1 = mfma16(FH12, bh, c1); c1 = mfma16(FL12, bh, c1); c1 = mfma16(FH12, bl, c1);
            bh = __builtin_bit_cast(s8v, g3); bl = __builtin_bit_cast(s8v, r3);
            c0 = mfma16(FH03, bh, c0); c0 = mfma16(FL03, bh, c0); c0 = mfma16(FH03, bl, c0);
            c1 = mfma16(FH13, bh, c1); c1 = mfma16(FL13, bh, c1); c1 = mfma16(FH13, bl, c1);
            const int rb = wb + q4*STRIDE + t*16 + ln;
            buf[rb           ] = packf(sin_om(c0.x));
            buf[rb +   STRIDE] = packf(sin_om(c0.y));
            buf[rb + 2*STRIDE] = packf(sin_om(c0.z));
            buf[rb + 3*STRIDE] = packf(sin_om(c0.w));
            buf[rb + 16*STRIDE] = packf(sin_om(c1.x));
            buf[rb + 17*STRIDE] = packf(sin_om(c1.y));
            buf[rb + 18*STRIDE] = packf(sin_om(c1.z));
            buf[rb + 19*STRIDE] = packf(sin_om(c1.w));
        }

        LAF8(RF)        // s1 A-fragments

        // ---- matmul2 -> s2; epilogue h = wgt2*(h + s2) ----
        LT8(ST5)
    }

    // ---- final linear head (fp32 VALU + shuffle reduce over ln) ----
#define LWF(nt) float WF##nt = wfp[nt*16+ln];
    LNT8(LWF)
#define HP(mt,reg) float P_##mt##_##reg = 0.f;
    LMR8(HP)
#define HACC(mt,nt,reg) P_##mt##_##reg = fmaf(WF##nt, H_##mt##_##nt##_##reg, P_##mt##_##reg);
    LH64(HACC)
#define HR(mt,reg) \
    P_##mt##_##reg += __shfl_xor(P_##mt##_##reg, 1); \
    P_##mt##_##reg += __shfl_xor(P_##mt##_##reg, 2); \
    P_##mt##_##reg += __shfl_xor(P_##mt##_##reg, 4); \
    P_##mt##_##reg += __shfl_xor(P_##mt##_##reg, 8);
    LMR8(HR)
    const float bf0 = bfp[0];
    if (ln == 0) {
#define HS(mt,reg) { int pt_ = base_pt + mt*16 + q4 + reg; \
        if (pt_ < NP) out[pt_] = P_##mt##_##reg + bf0; }
        LMR8(HS)
    }
}

extern "C" void kernel_launch(void* const* d_in, const int* in_sizes, int n_in,
                              void* d_out, int out_size, void* d_ws, size_t ws_size,
                              hipStream_t stream) {
    const float* x   = (const float*)d_in[0];
    const float* w0  = (const float*)d_in[1];
    const float* b0  = (const float*)d_in[2];
    const float* rw1 = (const float*)d_in[3];
    const float* rb1 = (const float*)d_in[4];
    const float* rw2 = (const float*)d_in[5];
    const float* rb2 = (const float*)d_in[6];
    const float* wf  = (const float*)d_in[7];
    const float* bf  = (const float*)d_in[8];
    float* out = (float*)d_out;

    unsigned short* wsHi = (unsigned short*)d_ws;          // needs 917504 B
    unsigned short* wsLo = wsHi + FRAG_ELEMS;

    const int n = in_sizes[0] / 3;                          // 200000
    prep_kernel<<<112, 256, 0, stream>>>(rw1, rw2, wsHi, wsLo);
    const int grid = (n + 127) / 128;
    siren_mfma<<<grid, BT, 0, stream>>>(x, w0, b0, rb1, rb2, wf, bf,
                                        (const u4v*)wsHi, (const u4v*)wsLo,
                                        out, n);
}